// Round 15
// baseline (309.435 us; speedup 1.0000x reference)
//
#include <hip/hip_runtime.h>
#include <hip/hip_bf16.h>
#include <math.h>

#define F_IN 128
#define TOT 192
#define HC 256
#define POS_DIM 64
#define XC 768   // 3 sections of 256: [xl | xr | ident], stored [3][n][256]

typedef __attribute__((ext_vector_type(8))) short bfrag8;
typedef __attribute__((ext_vector_type(4))) float facc4;
typedef __attribute__((ext_vector_type(2))) float f32x2;

__device__ __forceinline__ float bf2f(unsigned short u) {
  union { float f; unsigned int i; } x; x.i = ((unsigned int)u) << 16; return x.f;
}
__device__ __forceinline__ unsigned short f2bf(float f) {
  __hip_bfloat16 h = __float2bfloat16(f);
  return *(unsigned short*)&h;
}
// unpack 2 bf16 packed in a uint32 -> float2 (lo, hi)
__device__ __forceinline__ f32x2 bfpair(unsigned int u) {
  union { float f; unsigned int i; } lo, hi;
  lo.i = u << 16; hi.i = u & 0xffff0000u;
  f32x2 r; r.x = lo.f; r.y = hi.f; return r;
}

// v_add_f32 via DPP row_ror:N — full-rate VALU reduction within 16-lane rows.
#define ROR_ADD(s, CTRL) \
  s += __int_as_float(__builtin_amdgcn_update_dpp(0, __float_as_int(s), (CTRL), 0xF, 0xF, false))

// ---- fused weight prep: convert+transpose Wl/Wr/Wres -> w_cat[768][192],
// proj_w -> w_projb[256][256], and concat the 3 biases. One launch.
__global__ void k_wprep(const float* __restrict__ Wl, const float* __restrict__ Wr,
                        const float* __restrict__ Wres, const float* __restrict__ Wproj,
                        const float* __restrict__ b0, const float* __restrict__ b1,
                        const float* __restrict__ b2,
                        unsigned short* __restrict__ Bt, unsigned short* __restrict__ Btp,
                        float* __restrict__ bias_cat)
{
  int idx = blockIdx.x * 256 + threadIdx.x;
  const int N3 = 3 * TOT * HC;           // 147456
  const int NP = HC * HC;                // 65536
  if (idx < N3) {
    int w = idx / (TOT * HC), rem = idx % (TOT * HC);
    int k = rem / HC, c = rem % HC;
    const float* W = (w == 0) ? Wl : (w == 1) ? Wr : Wres;
    Bt[(size_t)(w * HC + c) * TOT + k] = f2bf(W[rem]);
  } else if (idx < N3 + NP) {
    int r = idx - N3;
    int k = r / HC, c = r % HC;
    Btp[(size_t)c * HC + k] = f2bf(Wproj[r]);
  } else if (idx < N3 + NP + 3 * HC) {
    int t = idx - N3 - NP;
    int sec = t >> 8, cw = t & 255;
    bias_cat[t] = (sec == 0) ? b0[cw] : (sec == 1) ? b1[cw] : b2[cw];
  }
}

// ---------------- node pos-encoder + x_comb build (4 nodes per block) ------
__global__ __launch_bounds__(256) void k_node(
    const float* __restrict__ x, const float* __restrict__ kpts, const float* __restrict__ pts3d,
    const float* __restrict__ pe_w1, const float* __restrict__ pe_b1,
    const float* __restrict__ pe_g1, const float* __restrict__ pe_bb1,
    const float* __restrict__ pe_w2, const float* __restrict__ pe_b2,
    const float* __restrict__ pe_g2, const float* __restrict__ pe_bb2,
    float* __restrict__ norm_uv, unsigned short* __restrict__ x_comb, int n)
{
  int tid = threadIdx.x;
  int wv = tid >> 6, lane = tid & 63;
  int node = blockIdx.x * 4 + wv;
  bool valid = node < n;
  int nd = valid ? node : 0;

  float u = kpts[nd*2+0] * (1.0f/1216.0f);
  float v = kpts[nd*2+1] * (1.0f/352.0f);
  float d = pts3d[nd*3+2];
  d = fminf(fmaxf(d, 0.1f), 100.0f);
  if (lane == 0 && valid) { norm_uv[nd*2] = u; norm_uv[nd*2+1] = v; }

  float a = 0.f;
  if (lane < 32)
    a = u*pe_w1[lane] + v*pe_w1[32+lane] + d*pe_w1[64+lane] + pe_b1[lane];
  float s = a, ss = a*a;
  #pragma unroll
  for (int m = 1; m < 32; m <<= 1) { s += __shfl_xor(s, m); ss += __shfl_xor(ss, m); }
  float mean = s * (1.f/32.f);
  float var  = ss * (1.f/32.f) - mean*mean;
  float inv  = rsqrtf(var + 1e-5f);
  __shared__ float hs[4][32];
  if (lane < 32) {
    float h = (a - mean) * inv * pe_g1[lane] + pe_bb1[lane];
    h = h / (1.f + __expf(-h));
    hs[wv][lane] = h;
  }
  __syncthreads();

  float pf = pe_b2[lane];
  #pragma unroll 8
  for (int j = 0; j < 32; j++) pf += hs[wv][j] * pe_w2[j*POS_DIM + lane];
  float s2 = pf, ss2 = pf*pf;
  #pragma unroll
  for (int m = 1; m < 64; m <<= 1) { s2 += __shfl_xor(s2, m); ss2 += __shfl_xor(ss2, m); }
  float mean2 = s2 * (1.f/64.f);
  float var2  = ss2 * (1.f/64.f) - mean2*mean2;
  float inv2  = rsqrtf(var2 + 1e-5f);
  pf = (pf - mean2) * inv2 * pe_g2[lane] + pe_bb2[lane];
  if (pf != pf) pf = 0.f;

  if (valid) {
    unsigned short* xc = x_comb + (size_t)nd * TOT;
    // vectorized copy: 64 lanes x float2 = 128 floats (F_IN)
    float2 xv = ((const float2*)(x + (size_t)nd * F_IN))[lane];
    float a0 = xv.x, a1 = xv.y;
    ushort2 o2;
    o2.x = f2bf((a0 != a0) ? 0.f : a0);
    o2.y = f2bf((a1 != a1) ? 0.f : a1);
    *(ushort2*)&xc[lane * 2] = o2;
    xc[F_IN + lane] = f2bf(pf);
  }
}

// ---------------- bf16 MFMA GEMM: C[M,Ncout] = A[M,K] @ B + bias -----------
// 1D grid + bijective XCD-chunked swizzle. A fragments direct global->VGPR;
// B staged in LDS (R13 lesson: LDS-free B starves the L1 port). M-tile=128:
// each wave computes TWO 16-row groups sharing the same B fragments, so
// every ds_read feeds 2 MFMAs and each staging+barrier pass serves 128 rows
// (halves the per-MFMA overhead that capped MfmaUtil at ~6.5%).
// BNT bn-tiles per block additionally reuse the A registers.
// SPLIT3: write output in [3][M][256] section-major layout.
template<int K, bool OUTBF, bool SPLIT3, int BNT>
__global__ __launch_bounds__(256) void k_mfma(
    const unsigned short* __restrict__ A,
    const unsigned short* __restrict__ Bt,
    const float* __restrict__ bias,
    void* __restrict__ Cout, int M, int Ncout)
{
  constexpr int KP = K + 8;
  __shared__ short Bs[64 * KP];

  int nbg = (Ncout >> 6) / BNT;
  int nwg = gridDim.x;
  int bid = blockIdx.x;
  int q = nwg >> 3, r = nwg & 7;
  int xcd = bid & 7, pos = bid >> 3;
  int wgid = ((xcd < r) ? xcd * (q + 1) : r * (q + 1) + (xcd - r) * q) + pos;
  int bm = (wgid / nbg) * 128;
  int bn0 = (wgid % nbg) * (BNT * 64);

  int tid = threadIdx.x;
  int wave = tid >> 6, lane = tid & 63;

  // A fragments: direct global->reg, two 16-row groups per wave
  int ar = wave * 16 + (lane & 15);
  int row0 = bm + ar;
  int row1 = row0 + 64;
  int kq = (lane >> 4) * 8;
  constexpr int NKB = K / 32;
  bfrag8 afr0[NKB], afr1[NKB];
  const unsigned short* Arow0 = A + (size_t)row0 * K + kq;
  const unsigned short* Arow1 = A + (size_t)row1 * K + kq;
  bfrag8 zf = {0,0,0,0,0,0,0,0};
  #pragma unroll
  for (int kk = 0; kk < NKB; kk++) {
    afr0[kk] = (row0 < M) ? *(const bfrag8*)&Arow0[kk * 32] : zf;
    afr1[kk] = (row1 < M) ? *(const bfrag8*)&Arow1[kk * 32] : zf;
  }

  constexpr int CH = K / 8;
  #pragma unroll
  for (int t = 0; t < BNT; t++) {
    int bn = bn0 + t * 64;
    if (t) __syncthreads();          // protect Bs overwrite from prior readers
    for (int idx = tid; idx < 64 * CH; idx += 256) {
      int r8 = idx / CH, c8 = idx % CH;
      *(uint4*)&Bs[r8 * KP + c8 * 8] = *(const uint4*)&Bt[(size_t)(bn + r8) * K + c8 * 8];
    }
    __syncthreads();

    facc4 acc0[4] = {{0,0,0,0},{0,0,0,0},{0,0,0,0},{0,0,0,0}};
    facc4 acc1[4] = {{0,0,0,0},{0,0,0,0},{0,0,0,0},{0,0,0,0}};
    #pragma unroll
    for (int kk = 0; kk < NKB; kk++) {
      int kb = kk * 32;
      #pragma unroll
      for (int nt = 0; nt < 4; nt++) {
        bfrag8 bfr = *(const bfrag8*)&Bs[(nt * 16 + (lane & 15)) * KP + kb + kq];
        acc0[nt] = __builtin_amdgcn_mfma_f32_16x16x32_bf16(afr0[kk], bfr, acc0[nt], 0, 0, 0);
        acc1[nt] = __builtin_amdgcn_mfma_f32_16x16x32_bf16(afr1[kk], bfr, acc1[nt], 0, 0, 0);
      }
    }

    int rbase0 = bm + wave * 16 + (lane >> 4) * 4;
    #pragma unroll
    for (int nt = 0; nt < 4; nt++) {
      int col = bn + nt * 16 + (lane & 15);
      float bi = bias[col];
      #pragma unroll
      for (int j = 0; j < 4; j++) {
        int rw0 = rbase0 + j;
        int rw1 = rw0 + 64;
        if (rw0 < M) {
          float v = acc0[nt][j] + bi;
          if (SPLIT3) {
            int sec = col >> 8, cw = col & 255;
            ((unsigned short*)Cout)[((size_t)sec * M + rw0) * HC + cw] = f2bf(v);
          } else if (OUTBF) {
            ((unsigned short*)Cout)[(size_t)rw0 * Ncout + col] = f2bf(v);
          } else {
            ((float*)Cout)[(size_t)rw0 * Ncout + col] = v;
          }
        }
        if (rw1 < M) {
          float v = acc1[nt][j] + bi;
          if (SPLIT3) {
            int sec = col >> 8, cw = col & 255;
            ((unsigned short*)Cout)[((size_t)sec * M + rw1) * HC + cw] = f2bf(v);
          } else if (OUTBF) {
            ((unsigned short*)Cout)[(size_t)rw1 * Ncout + col] = f2bf(v);
          } else {
            ((float*)Cout)[(size_t)rw1 * Ncout + col] = v;
          }
        }
      }
    }
  }
}

// ---------------- in-degree counts -----------------------------------------
__global__ void k_count(const int* __restrict__ ei, int* __restrict__ counts, int E)
{
  int e = blockIdx.x * blockDim.x + threadIdx.x;
  if (e < E) atomicAdd(&counts[ei[E + e]], 1);
}

// ---------------- 3-phase multi-block exclusive scan -----------------------
__global__ __launch_bounds__(256) void k_scan_part(const int* __restrict__ counts,
                                                   int* __restrict__ bsum, int n)
{
  int tid = threadIdx.x, lane = tid & 63;
  int base = blockIdx.x * 1024 + tid * 4;
  int s = 0;
  #pragma unroll
  for (int k = 0; k < 4; k++) { int i = base + k; if (i < n) s += counts[i]; }
  #pragma unroll
  for (int off = 1; off < 64; off <<= 1) s += __shfl_xor(s, off);
  __shared__ int wsum[4];
  if (lane == 0) wsum[tid >> 6] = s;
  __syncthreads();
  if (tid == 0) bsum[blockIdx.x] = wsum[0] + wsum[1] + wsum[2] + wsum[3];
}

__global__ __launch_bounds__(64) void k_scan_top(const int* __restrict__ bsum,
                                                 int* __restrict__ boff, int B)
{
  int lane = threadIdx.x;
  int carry = 0;
  for (int base = 0; base < B; base += 64) {
    int i = base + lane;
    int v = (i < B) ? bsum[i] : 0;
    int s = v;
    #pragma unroll
    for (int off = 1; off < 64; off <<= 1) {
      int t = __shfl_up(s, off);
      if (lane >= off) s += t;
    }
    if (i < B) boff[i] = carry + s - v;
    carry += __shfl(s, 63);
  }
}

__global__ __launch_bounds__(256) void k_scan_write(const int* __restrict__ counts,
                                                    const int* __restrict__ boff,
                                                    int* __restrict__ indptr,
                                                    int* __restrict__ cursor, int n)
{
  int tid = threadIdx.x, wv = tid >> 6, lane = tid & 63;
  int base = blockIdx.x * 1024 + tid * 4;
  int v[4]; int s = 0;
  #pragma unroll
  for (int k = 0; k < 4; k++) { int i = base + k; v[k] = (i < n) ? counts[i] : 0; s += v[k]; }
  int incl = s;
  #pragma unroll
  for (int off = 1; off < 64; off <<= 1) {
    int t = __shfl_up(incl, off);
    if (lane >= off) incl += t;
  }
  __shared__ int wsum[4];
  if (lane == 63) wsum[wv] = incl;
  __syncthreads();
  int woff = (wv > 0 ? wsum[0] : 0) + (wv > 1 ? wsum[1] : 0) + (wv > 2 ? wsum[2] : 0);
  int excl = boff[blockIdx.x] + woff + incl - s;
  #pragma unroll
  for (int k = 0; k < 4; k++) {
    int i = base + k;
    if (i < n) { indptr[i] = excl; cursor[i] = excl; }
    excl += v[k];
  }
}

// ---------------- edge_attr + packed CSR entry (src, rx, ry, dist) ---------
__global__ void k_edge_fill(const int* __restrict__ ei, const float* __restrict__ norm_uv,
                            float* __restrict__ eattr, int* __restrict__ cursor,
                            int4* __restrict__ csrp, int E)
{
  int e = blockIdx.x * blockDim.x + threadIdx.x;
  if (e >= E) return;
  int s = ei[e], d = ei[E + e];
  float rx = norm_uv[2*d]   - norm_uv[2*s];
  float ry = norm_uv[2*d+1] - norm_uv[2*s+1];
  float dist = sqrtf(rx*rx + ry*ry + 1e-9f);
  eattr[(size_t)e*3+0] = rx;
  eattr[(size_t)e*3+1] = ry;
  eattr[(size_t)e*3+2] = dist;
  int pos = atomicAdd(&cursor[d], 1);
  int4 ent;
  ent.x = s;
  ent.y = __float_as_int(rx);
  ent.z = __float_as_int(ry);
  ent.w = __float_as_int(dist);
  csrp[pos] = ent;
}

// ---------------- GAT aggregation: batched-prefetch edge pipeline ----------
// R5/R9-proven structure (82.3us, verified 5x): per 8-edge batch,
// (1) scalar-load 8 csrp entries into SGPRs back-to-back, (2) issue all 8
// row-gathers into distinct VGPRs, (3) compute. launch_bounds(64,8).
// Lessons: deeper pipelines (16-deep R6/R7, ping-pong R11) all spill past
// the 64-VGPR cap; lowering the bound loses occupancy. This is the optimum
// of this structure.
__global__ __launch_bounds__(64, 8) void k_gat2(
    const int* __restrict__ indptr, const int* __restrict__ counts,
    const int4* __restrict__ csrp,
    const unsigned short* __restrict__ xl,      // [n][256] dense gather target
    const unsigned short* __restrict__ xr_arr,  // [n][256]
    const unsigned short* __restrict__ id_arr,  // [n][256]
    const float* __restrict__ lin_edge_w, const float* __restrict__ att,
    const float* __restrict__ conv_bias,
    const float* __restrict__ norm_g, const float* __restrict__ norm_b,
    const float* __restrict__ post_g, const float* __restrict__ post_b,
    unsigned short* __restrict__ act, int n)
{
  int node = blockIdx.x;
  if (node >= n) return;
  int lane = threadIdx.x;
  int c0 = lane * 4;

  uint2 xru = *(const uint2*)&xr_arr[(size_t)node * HC + c0];
  f32x2 xrA = bfpair(xru.x), xrB = bfpair(xru.y);
  float4 w0 = *(const float4*)&lin_edge_w[0*HC + c0];
  float4 w1 = *(const float4*)&lin_edge_w[1*HC + c0];
  float4 w2 = *(const float4*)&lin_edge_w[2*HC + c0];
  float4 av = *(const float4*)&att[c0];
  f32x2 w0A = {w0.x, w0.y}, w0B = {w0.z, w0.w};
  f32x2 w1A = {w1.x, w1.y}, w1B = {w1.z, w1.w};
  f32x2 w2A = {w2.x, w2.y}, w2B = {w2.z, w2.w};
  f32x2 avA = {av.x, av.y}, avB = {av.z, av.w};
  int start = indptr[node], deg = counts[node];

  const char* xb = (const char*)xl;        // 32-bit byte offsets (25.6MB < 2^31)
  unsigned co2 = (unsigned)(c0 * 2);

  float l = 0.f;
  f32x2 accA = {0.f, 0.f}, accB = {0.f, 0.f};

  for (int j0 = 0; j0 < deg; j0 += 8) {
    int nb = deg - j0;               // uniform active count (>=1)
    // (1) batch the csrp scalar loads (clamped in-bounds, uniform addr)
    int4 e0, e1, e2, e3, e4, e5, e6, e7;
    {
      int dm1 = deg - 1;
      e0 = csrp[start + j0];
      e1 = csrp[start + ((j0+1 < deg) ? j0+1 : dm1)];
      e2 = csrp[start + ((j0+2 < deg) ? j0+2 : dm1)];
      e3 = csrp[start + ((j0+3 < deg) ? j0+3 : dm1)];
      e4 = csrp[start + ((j0+4 < deg) ? j0+4 : dm1)];
      e5 = csrp[start + ((j0+5 < deg) ? j0+5 : dm1)];
      e6 = csrp[start + ((j0+6 < deg) ? j0+6 : dm1)];
      e7 = csrp[start + ((j0+7 < deg) ? j0+7 : dm1)];
    }
    // (2) issue gathers for the active entries, back-to-back
    uint2 xu0, xu1, xu2, xu3, xu4, xu5, xu6, xu7;
    xu0 = *(const uint2*)(xb + ((unsigned)e0.x * (unsigned)(HC*2) + co2));
    if (nb > 1) xu1 = *(const uint2*)(xb + ((unsigned)e1.x * (unsigned)(HC*2) + co2));
    if (nb > 2) xu2 = *(const uint2*)(xb + ((unsigned)e2.x * (unsigned)(HC*2) + co2));
    if (nb > 3) xu3 = *(const uint2*)(xb + ((unsigned)e3.x * (unsigned)(HC*2) + co2));
    if (nb > 4) xu4 = *(const uint2*)(xb + ((unsigned)e4.x * (unsigned)(HC*2) + co2));
    if (nb > 5) xu5 = *(const uint2*)(xb + ((unsigned)e5.x * (unsigned)(HC*2) + co2));
    if (nb > 6) xu6 = *(const uint2*)(xb + ((unsigned)e6.x * (unsigned)(HC*2) + co2));
    if (nb > 7) xu7 = *(const uint2*)(xb + ((unsigned)e7.x * (unsigned)(HC*2) + co2));

    // (3) compute per active edge
    #define EDGE_COMPUTE(EE, XU)                                           \
    {                                                                      \
      float rx = __int_as_float(EE.y);                                     \
      float ry = __int_as_float(EE.z);                                     \
      float dd = __int_as_float(EE.w);                                     \
      f32x2 xA = bfpair(XU.x), xB = bfpair(XU.y);                          \
      f32x2 zA = xA + xrA + rx * w0A + ry * w1A + dd * w2A;                \
      f32x2 zB = xB + xrB + rx * w0B + ry * w1B + dd * w2B;                \
      zA = __builtin_elementwise_max(zA, zA * 0.2f);                       \
      zB = __builtin_elementwise_max(zB, zB * 0.2f);                       \
      f32x2 pv = zA * avA + zB * avB;                                      \
      float p = pv.x + pv.y;                                               \
      ROR_ADD(p, 0x121);                                                   \
      ROR_ADD(p, 0x122);                                                   \
      ROR_ADD(p, 0x124);                                                   \
      ROR_ADD(p, 0x128);                                                   \
      float w = __expf(p);                                                 \
      l += w;                                                              \
      accA += w * xA;                                                      \
      accB += w * xB;                                                      \
    }
    EDGE_COMPUTE(e0, xu0);
    if (nb > 1) EDGE_COMPUTE(e1, xu1);
    if (nb > 2) EDGE_COMPUTE(e2, xu2);
    if (nb > 3) EDGE_COMPUTE(e3, xu3);
    if (nb > 4) EDGE_COMPUTE(e4, xu4);
    if (nb > 5) EDGE_COMPUTE(e5, xu5);
    if (nb > 6) EDGE_COMPUTE(e6, xu6);
    if (nb > 7) EDGE_COMPUTE(e7, xu7);
    #undef EDGE_COMPUTE
  }

  float invl = 1.f / (l + 1e-16f);
  float4 cb = *(const float4*)&conv_bias[c0];
  float t0 = accA.x*invl + cb.x, t1 = accA.y*invl + cb.y;
  float t2 = accB.x*invl + cb.z, t3 = accB.y*invl + cb.w;

  // ---- fused epilogue: LN -> +identity -> SiLU -> LN -> bf16 ----
  float s1 = t0+t1+t2+t3;
  float q1 = t0*t0 + t1*t1 + t2*t2 + t3*t3;
  #pragma unroll
  for (int mm = 1; mm < 64; mm <<= 1) { s1 += __shfl_xor(s1, mm); q1 += __shfl_xor(q1, mm); }
  float mean = s1 * (1.f/256.f);
  float var  = q1 * (1.f/256.f) - mean*mean;
  float inv  = rsqrtf(var + 1e-5f);
  float4 g = *(const float4*)&norm_g[c0];
  float4 b = *(const float4*)&norm_b[c0];
  ushort4 idu = *(const ushort4*)&id_arr[(size_t)node * HC + c0];
  float u0 = (t0-mean)*inv*g.x + b.x + bf2f(idu.x);
  float u1 = (t1-mean)*inv*g.y + b.y + bf2f(idu.y);
  float u2 = (t2-mean)*inv*g.z + b.z + bf2f(idu.z);
  float u3 = (t3-mean)*inv*g.w + b.w + bf2f(idu.w);
  u0 = u0 / (1.f + __expf(-u0));
  u1 = u1 / (1.f + __expf(-u1));
  u2 = u2 / (1.f + __expf(-u2));
  u3 = u3 / (1.f + __expf(-u3));
  float s2 = u0+u1+u2+u3;
  float q2 = u0*u0 + u1*u1 + u2*u2 + u3*u3;
  #pragma unroll
  for (int mm = 1; mm < 64; mm <<= 1) { s2 += __shfl_xor(s2, mm); q2 += __shfl_xor(q2, mm); }
  float mean2 = s2 * (1.f/256.f);
  float var2  = q2 * (1.f/256.f) - mean2*mean2;
  float inv2  = rsqrtf(var2 + 1e-5f);
  float4 g2 = *(const float4*)&post_g[c0];
  float4 b2 = *(const float4*)&post_b[c0];
  ushort4 o;
  o.x = f2bf((u0-mean2)*inv2*g2.x + b2.x);
  o.y = f2bf((u1-mean2)*inv2*g2.y + b2.y);
  o.z = f2bf((u2-mean2)*inv2*g2.z + b2.z);
  o.w = f2bf((u3-mean2)*inv2*g2.w + b2.w);
  *(ushort4*)&act[(size_t)node*HC + c0] = o;
}

// ---------------------------------------------------------------------------
extern "C" void kernel_launch(void* const* d_in, const int* in_sizes, int n_in,
                              void* d_out, int out_size, void* d_ws, size_t ws_size,
                              hipStream_t stream)
{
  const float* x        = (const float*)d_in[0];
  const int*   ei       = (const int*)  d_in[1];
  const float* kpts     = (const float*)d_in[2];
  const float* pts3d    = (const float*)d_in[3];
  const float* pe_w1    = (const float*)d_in[4];
  const float* pe_b1    = (const float*)d_in[5];
  const float* pe_g1    = (const float*)d_in[6];
  const float* pe_bb1   = (const float*)d_in[7];
  const float* pe_w2    = (const float*)d_in[8];
  const float* pe_b2    = (const float*)d_in[9];
  const float* pe_g2    = (const float*)d_in[10];
  const float* pe_bb2   = (const float*)d_in[11];
  const float* lin_l_w  = (const float*)d_in[12];
  const float* lin_l_b  = (const float*)d_in[13];
  const float* lin_r_w  = (const float*)d_in[14];
  const float* lin_r_b  = (const float*)d_in[15];
  const float* lin_edge_w = (const float*)d_in[16];
  const float* att      = (const float*)d_in[17];
  const float* conv_bias= (const float*)d_in[18];
  const float* res_w    = (const float*)d_in[19];
  const float* res_b    = (const float*)d_in[20];
  const float* norm_g   = (const float*)d_in[21];
  const float* norm_b   = (const float*)d_in[22];
  const float* post_g   = (const float*)d_in[23];
  const float* post_b   = (const float*)d_in[24];
  const float* proj_w   = (const float*)d_in[25];
  const float* proj_b   = (const float*)d_in[26];

  int n = in_sizes[0] / F_IN;
  int E = in_sizes[1] / 2;

  char* base = (char*)d_ws;
  size_t off = 0;
  auto alloc = [&](size_t bytes) -> void* {
    void* p = base + off;
    off = (off + bytes + 255) & ~(size_t)255;
    return p;
  };
  float*          norm_uv = (float*)         alloc((size_t)2*n*4);
  unsigned short* x_comb  = (unsigned short*)alloc((size_t)n*TOT*2);
  unsigned short* xcat    = (unsigned short*)alloc((size_t)n*XC*2);  // [3][n][256]
  unsigned short* act     = (unsigned short*)alloc((size_t)n*HC*2);
  unsigned short* w_cat   = (unsigned short*)alloc((size_t)XC*TOT*2);
  unsigned short* w_projb = (unsigned short*)alloc((size_t)HC*HC*2);
  float*          bias_cat= (float*)         alloc((size_t)XC*4);
  int* counts = (int*)alloc((size_t)n*4);
  int* indptr = (int*)alloc((size_t)n*4);
  int* cursor = (int*)alloc((size_t)n*4);
  int4* csrp  = (int4*)alloc((size_t)E*16);
  int  B      = (n + 1023) / 1024;
  int* bsum   = (int*)alloc((size_t)B*4);
  int* boff   = (int*)alloc((size_t)B*4);

  unsigned short* xl_arr = xcat;
  unsigned short* xr_arr = xcat + (size_t)n * HC;
  unsigned short* id_arr = xcat + (size_t)2 * n * HC;

  float* out_final = (float*)d_out;
  float* eattr     = out_final + (size_t)n*HC;

  (void)hipMemsetAsync(counts, 0, (size_t)n*sizeof(int), stream);

  int wtot = 3*TOT*HC + HC*HC + 3*HC;
  k_wprep<<<(wtot + 255)/256, 256, 0, stream>>>(lin_l_w, lin_r_w, res_w, proj_w,
                                                lin_l_b, lin_r_b, res_b,
                                                w_cat, w_projb, bias_cat);

  k_node<<<(n + 3)/4, 256, 0, stream>>>(x, kpts, pts3d, pe_w1, pe_b1, pe_g1, pe_bb1,
                                        pe_w2, pe_b2, pe_g2, pe_bb2, norm_uv, x_comb, n);

  int nbm2 = (n + 127) / 128;
  k_mfma<TOT, true, true, 2><<<nbm2 * (XC/128), 256, 0, stream>>>(x_comb, w_cat, bias_cat, xcat, n, XC);

  int eb = (E + 255) / 256;
  k_count<<<eb, 256, 0, stream>>>(ei, counts, E);
  k_scan_part <<<B, 256, 0, stream>>>(counts, bsum, n);
  k_scan_top  <<<1, 64, 0, stream>>>(bsum, boff, B);
  k_scan_write<<<B, 256, 0, stream>>>(counts, boff, indptr, cursor, n);
  k_edge_fill<<<eb, 256, 0, stream>>>(ei, norm_uv, eattr, cursor, csrp, E);

  k_gat2<<<n, 64, 0, stream>>>(indptr, counts, csrp, xl_arr, xr_arr, id_arr,
                               lin_edge_w, att, conv_bias,
                               norm_g, norm_b, post_g, post_b, act, n);

  k_mfma<HC, false, false, 2><<<nbm2 * (HC/128), 256, 0, stream>>>(act, w_projb, proj_b, out_final, n, HC);
}

// Round 16
// 283.801 us; speedup vs baseline: 1.0903x; 1.0903x over previous
//
#include <hip/hip_runtime.h>
#include <hip/hip_bf16.h>
#include <math.h>

#define F_IN 128
#define TOT 192
#define HC 256
#define POS_DIM 64
#define XC 768   // 3 sections of 256: [xl | xr | ident], stored [3][n][256]

typedef __attribute__((ext_vector_type(8))) short bfrag8;
typedef __attribute__((ext_vector_type(4))) float facc4;
typedef __attribute__((ext_vector_type(2))) float f32x2;

__device__ __forceinline__ float bf2f(unsigned short u) {
  union { float f; unsigned int i; } x; x.i = ((unsigned int)u) << 16; return x.f;
}
__device__ __forceinline__ unsigned short f2bf(float f) {
  __hip_bfloat16 h = __float2bfloat16(f);
  return *(unsigned short*)&h;
}
// unpack 2 bf16 packed in a uint32 -> float2 (lo, hi)
__device__ __forceinline__ f32x2 bfpair(unsigned int u) {
  union { float f; unsigned int i; } lo, hi;
  lo.i = u << 16; hi.i = u & 0xffff0000u;
  f32x2 r; r.x = lo.f; r.y = hi.f; return r;
}

// v_add_f32 via DPP row_ror:N — full-rate VALU reduction within 16-lane rows.
#define ROR_ADD(s, CTRL) \
  s += __int_as_float(__builtin_amdgcn_update_dpp(0, __float_as_int(s), (CTRL), 0xF, 0xF, false))

// ---- fused weight prep: convert+transpose Wl/Wr/Wres -> w_cat[768][192],
// proj_w -> w_projb[256][256], and concat the 3 biases. One launch.
__global__ void k_wprep(const float* __restrict__ Wl, const float* __restrict__ Wr,
                        const float* __restrict__ Wres, const float* __restrict__ Wproj,
                        const float* __restrict__ b0, const float* __restrict__ b1,
                        const float* __restrict__ b2,
                        unsigned short* __restrict__ Bt, unsigned short* __restrict__ Btp,
                        float* __restrict__ bias_cat)
{
  int idx = blockIdx.x * 256 + threadIdx.x;
  const int N3 = 3 * TOT * HC;           // 147456
  const int NP = HC * HC;                // 65536
  if (idx < N3) {
    int w = idx / (TOT * HC), rem = idx % (TOT * HC);
    int k = rem / HC, c = rem % HC;
    const float* W = (w == 0) ? Wl : (w == 1) ? Wr : Wres;
    Bt[(size_t)(w * HC + c) * TOT + k] = f2bf(W[rem]);
  } else if (idx < N3 + NP) {
    int r = idx - N3;
    int k = r / HC, c = r % HC;
    Btp[(size_t)c * HC + k] = f2bf(Wproj[r]);
  } else if (idx < N3 + NP + 3 * HC) {
    int t = idx - N3 - NP;
    int sec = t >> 8, cw = t & 255;
    bias_cat[t] = (sec == 0) ? b0[cw] : (sec == 1) ? b1[cw] : b2[cw];
  }
}

// ---------------- node pos-encoder + x_comb build (4 nodes per block) ------
__global__ __launch_bounds__(256) void k_node(
    const float* __restrict__ x, const float* __restrict__ kpts, const float* __restrict__ pts3d,
    const float* __restrict__ pe_w1, const float* __restrict__ pe_b1,
    const float* __restrict__ pe_g1, const float* __restrict__ pe_bb1,
    const float* __restrict__ pe_w2, const float* __restrict__ pe_b2,
    const float* __restrict__ pe_g2, const float* __restrict__ pe_bb2,
    float* __restrict__ norm_uv, unsigned short* __restrict__ x_comb, int n)
{
  int tid = threadIdx.x;
  int wv = tid >> 6, lane = tid & 63;
  int node = blockIdx.x * 4 + wv;
  bool valid = node < n;
  int nd = valid ? node : 0;

  float u = kpts[nd*2+0] * (1.0f/1216.0f);
  float v = kpts[nd*2+1] * (1.0f/352.0f);
  float d = pts3d[nd*3+2];
  d = fminf(fmaxf(d, 0.1f), 100.0f);
  if (lane == 0 && valid) { norm_uv[nd*2] = u; norm_uv[nd*2+1] = v; }

  float a = 0.f;
  if (lane < 32)
    a = u*pe_w1[lane] + v*pe_w1[32+lane] + d*pe_w1[64+lane] + pe_b1[lane];
  float s = a, ss = a*a;
  #pragma unroll
  for (int m = 1; m < 32; m <<= 1) { s += __shfl_xor(s, m); ss += __shfl_xor(ss, m); }
  float mean = s * (1.f/32.f);
  float var  = ss * (1.f/32.f) - mean*mean;
  float inv  = rsqrtf(var + 1e-5f);
  __shared__ float hs[4][32];
  if (lane < 32) {
    float h = (a - mean) * inv * pe_g1[lane] + pe_bb1[lane];
    h = h / (1.f + __expf(-h));
    hs[wv][lane] = h;
  }
  __syncthreads();

  float pf = pe_b2[lane];
  #pragma unroll 8
  for (int j = 0; j < 32; j++) pf += hs[wv][j] * pe_w2[j*POS_DIM + lane];
  float s2 = pf, ss2 = pf*pf;
  #pragma unroll
  for (int m = 1; m < 64; m <<= 1) { s2 += __shfl_xor(s2, m); ss2 += __shfl_xor(ss2, m); }
  float mean2 = s2 * (1.f/64.f);
  float var2  = ss2 * (1.f/64.f) - mean2*mean2;
  float inv2  = rsqrtf(var2 + 1e-5f);
  pf = (pf - mean2) * inv2 * pe_g2[lane] + pe_bb2[lane];
  if (pf != pf) pf = 0.f;

  if (valid) {
    unsigned short* xc = x_comb + (size_t)nd * TOT;
    // vectorized copy: 64 lanes x float2 = 128 floats (F_IN)
    float2 xv = ((const float2*)(x + (size_t)nd * F_IN))[lane];
    float a0 = xv.x, a1 = xv.y;
    ushort2 o2;
    o2.x = f2bf((a0 != a0) ? 0.f : a0);
    o2.y = f2bf((a1 != a1) ? 0.f : a1);
    *(ushort2*)&xc[lane * 2] = o2;
    xc[F_IN + lane] = f2bf(pf);
  }
}

// ---------------- bf16 MFMA GEMM: C[M,Ncout] = A[M,K] @ B + bias -----------
// R12/R14-proven form (287us total, reproduced twice). 1D grid + bijective
// XCD-chunked swizzle. A fragments direct global->VGPR (zero cross-wave
// reuse); B staged in LDS (R13 lesson: LDS-free B starves the L1 port;
// R15 lesson: M-tile 128 doubles VGPR and loses more occupancy than the
// amortization gains). BNT bn-tiles per block reuse the A registers.
// SPLIT3: write output in [3][M][256] section-major layout.
template<int K, bool OUTBF, bool SPLIT3, int BNT>
__global__ __launch_bounds__(256) void k_mfma(
    const unsigned short* __restrict__ A,
    const unsigned short* __restrict__ Bt,
    const float* __restrict__ bias,
    void* __restrict__ Cout, int M, int Ncout)
{
  constexpr int KP = K + 8;
  __shared__ short Bs[64 * KP];

  int nbg = (Ncout >> 6) / BNT;
  int nwg = gridDim.x;
  int bid = blockIdx.x;
  int q = nwg >> 3, r = nwg & 7;
  int xcd = bid & 7, pos = bid >> 3;
  int wgid = ((xcd < r) ? xcd * (q + 1) : r * (q + 1) + (xcd - r) * q) + pos;
  int bm = (wgid / nbg) * 64;
  int bn0 = (wgid % nbg) * (BNT * 64);

  int tid = threadIdx.x;
  int wave = tid >> 6, lane = tid & 63;

  // A fragments: direct global->reg (no LDS round-trip, no cross-wave reuse)
  int ar = wave * 16 + (lane & 15);
  int row = bm + ar;
  int kq = (lane >> 4) * 8;
  constexpr int NKB = K / 32;
  bfrag8 afr[NKB];
  const unsigned short* Arow = A + (size_t)row * K + kq;
  bfrag8 zf = {0,0,0,0,0,0,0,0};
  #pragma unroll
  for (int kk = 0; kk < NKB; kk++)
    afr[kk] = (row < M) ? *(const bfrag8*)&Arow[kk * 32] : zf;

  constexpr int CH = K / 8;
  #pragma unroll
  for (int t = 0; t < BNT; t++) {
    int bn = bn0 + t * 64;
    if (t) __syncthreads();          // protect Bs overwrite from prior readers
    for (int idx = tid; idx < 64 * CH; idx += 256) {
      int r8 = idx / CH, c8 = idx % CH;
      *(uint4*)&Bs[r8 * KP + c8 * 8] = *(const uint4*)&Bt[(size_t)(bn + r8) * K + c8 * 8];
    }
    __syncthreads();

    facc4 acc[4] = {{0,0,0,0},{0,0,0,0},{0,0,0,0},{0,0,0,0}};
    #pragma unroll
    for (int kk = 0; kk < NKB; kk++) {
      int kb = kk * 32;
      #pragma unroll
      for (int nt = 0; nt < 4; nt++) {
        bfrag8 bfr = *(const bfrag8*)&Bs[(nt * 16 + (lane & 15)) * KP + kb + kq];
        acc[nt] = __builtin_amdgcn_mfma_f32_16x16x32_bf16(afr[kk], bfr, acc[nt], 0, 0, 0);
      }
    }

    int rbase = bm + wave * 16 + (lane >> 4) * 4;
    #pragma unroll
    for (int nt = 0; nt < 4; nt++) {
      int col = bn + nt * 16 + (lane & 15);
      float bi = bias[col];
      #pragma unroll
      for (int j = 0; j < 4; j++) {
        int rw = rbase + j;
        if (rw < M) {
          float v = acc[nt][j] + bi;
          if (SPLIT3) {
            int sec = col >> 8, cw = col & 255;
            ((unsigned short*)Cout)[((size_t)sec * M + rw) * HC + cw] = f2bf(v);
          } else if (OUTBF) {
            ((unsigned short*)Cout)[(size_t)rw * Ncout + col] = f2bf(v);
          } else {
            ((float*)Cout)[(size_t)rw * Ncout + col] = v;
          }
        }
      }
    }
  }
}

// ---------------- in-degree counts -----------------------------------------
__global__ void k_count(const int* __restrict__ ei, int* __restrict__ counts, int E)
{
  int e = blockIdx.x * blockDim.x + threadIdx.x;
  if (e < E) atomicAdd(&counts[ei[E + e]], 1);
}

// ---------------- 3-phase multi-block exclusive scan -----------------------
__global__ __launch_bounds__(256) void k_scan_part(const int* __restrict__ counts,
                                                   int* __restrict__ bsum, int n)
{
  int tid = threadIdx.x, lane = tid & 63;
  int base = blockIdx.x * 1024 + tid * 4;
  int s = 0;
  #pragma unroll
  for (int k = 0; k < 4; k++) { int i = base + k; if (i < n) s += counts[i]; }
  #pragma unroll
  for (int off = 1; off < 64; off <<= 1) s += __shfl_xor(s, off);
  __shared__ int wsum[4];
  if (lane == 0) wsum[tid >> 6] = s;
  __syncthreads();
  if (tid == 0) bsum[blockIdx.x] = wsum[0] + wsum[1] + wsum[2] + wsum[3];
}

__global__ __launch_bounds__(64) void k_scan_top(const int* __restrict__ bsum,
                                                 int* __restrict__ boff, int B)
{
  int lane = threadIdx.x;
  int carry = 0;
  for (int base = 0; base < B; base += 64) {
    int i = base + lane;
    int v = (i < B) ? bsum[i] : 0;
    int s = v;
    #pragma unroll
    for (int off = 1; off < 64; off <<= 1) {
      int t = __shfl_up(s, off);
      if (lane >= off) s += t;
    }
    if (i < B) boff[i] = carry + s - v;
    carry += __shfl(s, 63);
  }
}

__global__ __launch_bounds__(256) void k_scan_write(const int* __restrict__ counts,
                                                    const int* __restrict__ boff,
                                                    int* __restrict__ indptr,
                                                    int* __restrict__ cursor, int n)
{
  int tid = threadIdx.x, wv = tid >> 6, lane = tid & 63;
  int base = blockIdx.x * 1024 + tid * 4;
  int v[4]; int s = 0;
  #pragma unroll
  for (int k = 0; k < 4; k++) { int i = base + k; v[k] = (i < n) ? counts[i] : 0; s += v[k]; }
  int incl = s;
  #pragma unroll
  for (int off = 1; off < 64; off <<= 1) {
    int t = __shfl_up(incl, off);
    if (lane >= off) incl += t;
  }
  __shared__ int wsum[4];
  if (lane == 63) wsum[wv] = incl;
  __syncthreads();
  int woff = (wv > 0 ? wsum[0] : 0) + (wv > 1 ? wsum[1] : 0) + (wv > 2 ? wsum[2] : 0);
  int excl = boff[blockIdx.x] + woff + incl - s;
  #pragma unroll
  for (int k = 0; k < 4; k++) {
    int i = base + k;
    if (i < n) { indptr[i] = excl; cursor[i] = excl; }
    excl += v[k];
  }
}

// ---------------- edge_attr + packed CSR entry (src, rx, ry, dist) ---------
__global__ void k_edge_fill(const int* __restrict__ ei, const float* __restrict__ norm_uv,
                            float* __restrict__ eattr, int* __restrict__ cursor,
                            int4* __restrict__ csrp, int E)
{
  int e = blockIdx.x * blockDim.x + threadIdx.x;
  if (e >= E) return;
  int s = ei[e], d = ei[E + e];
  float rx = norm_uv[2*d]   - norm_uv[2*s];
  float ry = norm_uv[2*d+1] - norm_uv[2*s+1];
  float dist = sqrtf(rx*rx + ry*ry + 1e-9f);
  eattr[(size_t)e*3+0] = rx;
  eattr[(size_t)e*3+1] = ry;
  eattr[(size_t)e*3+2] = dist;
  int pos = atomicAdd(&cursor[d], 1);
  int4 ent;
  ent.x = s;
  ent.y = __float_as_int(rx);
  ent.z = __float_as_int(ry);
  ent.w = __float_as_int(dist);
  csrp[pos] = ent;
}

// ---------------- GAT aggregation: batched-prefetch edge pipeline ----------
// R5/R9-proven structure (82.3us, verified 6x): per 8-edge batch,
// (1) scalar-load 8 csrp entries into SGPRs back-to-back, (2) issue all 8
// row-gathers into distinct VGPRs, (3) compute. launch_bounds(64,8).
// Lessons: deeper pipelines (16-deep R6/R7, ping-pong R11) all spill past
// the 64-VGPR cap; lowering the bound loses occupancy. This is the optimum
// of this structure.
__global__ __launch_bounds__(64, 8) void k_gat2(
    const int* __restrict__ indptr, const int* __restrict__ counts,
    const int4* __restrict__ csrp,
    const unsigned short* __restrict__ xl,      // [n][256] dense gather target
    const unsigned short* __restrict__ xr_arr,  // [n][256]
    const unsigned short* __restrict__ id_arr,  // [n][256]
    const float* __restrict__ lin_edge_w, const float* __restrict__ att,
    const float* __restrict__ conv_bias,
    const float* __restrict__ norm_g, const float* __restrict__ norm_b,
    const float* __restrict__ post_g, const float* __restrict__ post_b,
    unsigned short* __restrict__ act, int n)
{
  int node = blockIdx.x;
  if (node >= n) return;
  int lane = threadIdx.x;
  int c0 = lane * 4;

  uint2 xru = *(const uint2*)&xr_arr[(size_t)node * HC + c0];
  f32x2 xrA = bfpair(xru.x), xrB = bfpair(xru.y);
  float4 w0 = *(const float4*)&lin_edge_w[0*HC + c0];
  float4 w1 = *(const float4*)&lin_edge_w[1*HC + c0];
  float4 w2 = *(const float4*)&lin_edge_w[2*HC + c0];
  float4 av = *(const float4*)&att[c0];
  f32x2 w0A = {w0.x, w0.y}, w0B = {w0.z, w0.w};
  f32x2 w1A = {w1.x, w1.y}, w1B = {w1.z, w1.w};
  f32x2 w2A = {w2.x, w2.y}, w2B = {w2.z, w2.w};
  f32x2 avA = {av.x, av.y}, avB = {av.z, av.w};
  int start = indptr[node], deg = counts[node];

  const char* xb = (const char*)xl;        // 32-bit byte offsets (25.6MB < 2^31)
  unsigned co2 = (unsigned)(c0 * 2);

  float l = 0.f;
  f32x2 accA = {0.f, 0.f}, accB = {0.f, 0.f};

  for (int j0 = 0; j0 < deg; j0 += 8) {
    int nb = deg - j0;               // uniform active count (>=1)
    // (1) batch the csrp scalar loads (clamped in-bounds, uniform addr)
    int4 e0, e1, e2, e3, e4, e5, e6, e7;
    {
      int dm1 = deg - 1;
      e0 = csrp[start + j0];
      e1 = csrp[start + ((j0+1 < deg) ? j0+1 : dm1)];
      e2 = csrp[start + ((j0+2 < deg) ? j0+2 : dm1)];
      e3 = csrp[start + ((j0+3 < deg) ? j0+3 : dm1)];
      e4 = csrp[start + ((j0+4 < deg) ? j0+4 : dm1)];
      e5 = csrp[start + ((j0+5 < deg) ? j0+5 : dm1)];
      e6 = csrp[start + ((j0+6 < deg) ? j0+6 : dm1)];
      e7 = csrp[start + ((j0+7 < deg) ? j0+7 : dm1)];
    }
    // (2) issue gathers for the active entries, back-to-back
    uint2 xu0, xu1, xu2, xu3, xu4, xu5, xu6, xu7;
    xu0 = *(const uint2*)(xb + ((unsigned)e0.x * (unsigned)(HC*2) + co2));
    if (nb > 1) xu1 = *(const uint2*)(xb + ((unsigned)e1.x * (unsigned)(HC*2) + co2));
    if (nb > 2) xu2 = *(const uint2*)(xb + ((unsigned)e2.x * (unsigned)(HC*2) + co2));
    if (nb > 3) xu3 = *(const uint2*)(xb + ((unsigned)e3.x * (unsigned)(HC*2) + co2));
    if (nb > 4) xu4 = *(const uint2*)(xb + ((unsigned)e4.x * (unsigned)(HC*2) + co2));
    if (nb > 5) xu5 = *(const uint2*)(xb + ((unsigned)e5.x * (unsigned)(HC*2) + co2));
    if (nb > 6) xu6 = *(const uint2*)(xb + ((unsigned)e6.x * (unsigned)(HC*2) + co2));
    if (nb > 7) xu7 = *(const uint2*)(xb + ((unsigned)e7.x * (unsigned)(HC*2) + co2));

    // (3) compute per active edge
    #define EDGE_COMPUTE(EE, XU)                                           \
    {                                                                      \
      float rx = __int_as_float(EE.y);                                     \
      float ry = __int_as_float(EE.z);                                     \
      float dd = __int_as_float(EE.w);                                     \
      f32x2 xA = bfpair(XU.x), xB = bfpair(XU.y);                          \
      f32x2 zA = xA + xrA + rx * w0A + ry * w1A + dd * w2A;                \
      f32x2 zB = xB + xrB + rx * w0B + ry * w1B + dd * w2B;                \
      zA = __builtin_elementwise_max(zA, zA * 0.2f);                       \
      zB = __builtin_elementwise_max(zB, zB * 0.2f);                       \
      f32x2 pv = zA * avA + zB * avB;                                      \
      float p = pv.x + pv.y;                                               \
      ROR_ADD(p, 0x121);                                                   \
      ROR_ADD(p, 0x122);                                                   \
      ROR_ADD(p, 0x124);                                                   \
      ROR_ADD(p, 0x128);                                                   \
      float w = __expf(p);                                                 \
      l += w;                                                              \
      accA += w * xA;                                                      \
      accB += w * xB;                                                      \
    }
    EDGE_COMPUTE(e0, xu0);
    if (nb > 1) EDGE_COMPUTE(e1, xu1);
    if (nb > 2) EDGE_COMPUTE(e2, xu2);
    if (nb > 3) EDGE_COMPUTE(e3, xu3);
    if (nb > 4) EDGE_COMPUTE(e4, xu4);
    if (nb > 5) EDGE_COMPUTE(e5, xu5);
    if (nb > 6) EDGE_COMPUTE(e6, xu6);
    if (nb > 7) EDGE_COMPUTE(e7, xu7);
    #undef EDGE_COMPUTE
  }

  float invl = 1.f / (l + 1e-16f);
  float4 cb = *(const float4*)&conv_bias[c0];
  float t0 = accA.x*invl + cb.x, t1 = accA.y*invl + cb.y;
  float t2 = accB.x*invl + cb.z, t3 = accB.y*invl + cb.w;

  // ---- fused epilogue: LN -> +identity -> SiLU -> LN -> bf16 ----
  float s1 = t0+t1+t2+t3;
  float q1 = t0*t0 + t1*t1 + t2*t2 + t3*t3;
  #pragma unroll
  for (int mm = 1; mm < 64; mm <<= 1) { s1 += __shfl_xor(s1, mm); q1 += __shfl_xor(q1, mm); }
  float mean = s1 * (1.f/256.f);
  float var  = q1 * (1.f/256.f) - mean*mean;
  float inv  = rsqrtf(var + 1e-5f);
  float4 g = *(const float4*)&norm_g[c0];
  float4 b = *(const float4*)&norm_b[c0];
  ushort4 idu = *(const ushort4*)&id_arr[(size_t)node * HC + c0];
  float u0 = (t0-mean)*inv*g.x + b.x + bf2f(idu.x);
  float u1 = (t1-mean)*inv*g.y + b.y + bf2f(idu.y);
  float u2 = (t2-mean)*inv*g.z + b.z + bf2f(idu.z);
  float u3 = (t3-mean)*inv*g.w + b.w + bf2f(idu.w);
  u0 = u0 / (1.f + __expf(-u0));
  u1 = u1 / (1.f + __expf(-u1));
  u2 = u2 / (1.f + __expf(-u2));
  u3 = u3 / (1.f + __expf(-u3));
  float s2 = u0+u1+u2+u3;
  float q2 = u0*u0 + u1*u1 + u2*u2 + u3*u3;
  #pragma unroll
  for (int mm = 1; mm < 64; mm <<= 1) { s2 += __shfl_xor(s2, mm); q2 += __shfl_xor(q2, mm); }
  float mean2 = s2 * (1.f/256.f);
  float var2  = q2 * (1.f/256.f) - mean2*mean2;
  float inv2  = rsqrtf(var2 + 1e-5f);
  float4 g2 = *(const float4*)&post_g[c0];
  float4 b2 = *(const float4*)&post_b[c0];
  ushort4 o;
  o.x = f2bf((u0-mean2)*inv2*g2.x + b2.x);
  o.y = f2bf((u1-mean2)*inv2*g2.y + b2.y);
  o.z = f2bf((u2-mean2)*inv2*g2.z + b2.z);
  o.w = f2bf((u3-mean2)*inv2*g2.w + b2.w);
  *(ushort4*)&act[(size_t)node*HC + c0] = o;
}

// ---------------------------------------------------------------------------
extern "C" void kernel_launch(void* const* d_in, const int* in_sizes, int n_in,
                              void* d_out, int out_size, void* d_ws, size_t ws_size,
                              hipStream_t stream)
{
  const float* x        = (const float*)d_in[0];
  const int*   ei       = (const int*)  d_in[1];
  const float* kpts     = (const float*)d_in[2];
  const float* pts3d    = (const float*)d_in[3];
  const float* pe_w1    = (const float*)d_in[4];
  const float* pe_b1    = (const float*)d_in[5];
  const float* pe_g1    = (const float*)d_in[6];
  const float* pe_bb1   = (const float*)d_in[7];
  const float* pe_w2    = (const float*)d_in[8];
  const float* pe_b2    = (const float*)d_in[9];
  const float* pe_g2    = (const float*)d_in[10];
  const float* pe_bb2   = (const float*)d_in[11];
  const float* lin_l_w  = (const float*)d_in[12];
  const float* lin_l_b  = (const float*)d_in[13];
  const float* lin_r_w  = (const float*)d_in[14];
  const float* lin_r_b  = (const float*)d_in[15];
  const float* lin_edge_w = (const float*)d_in[16];
  const float* att      = (const float*)d_in[17];
  const float* conv_bias= (const float*)d_in[18];
  const float* res_w    = (const float*)d_in[19];
  const float* res_b    = (const float*)d_in[20];
  const float* norm_g   = (const float*)d_in[21];
  const float* norm_b   = (const float*)d_in[22];
  const float* post_g   = (const float*)d_in[23];
  const float* post_b   = (const float*)d_in[24];
  const float* proj_w   = (const float*)d_in[25];
  const float* proj_b   = (const float*)d_in[26];

  int n = in_sizes[0] / F_IN;
  int E = in_sizes[1] / 2;

  char* base = (char*)d_ws;
  size_t off = 0;
  auto alloc = [&](size_t bytes) -> void* {
    void* p = base + off;
    off = (off + bytes + 255) & ~(size_t)255;
    return p;
  };
  float*          norm_uv = (float*)         alloc((size_t)2*n*4);
  unsigned short* x_comb  = (unsigned short*)alloc((size_t)n*TOT*2);
  unsigned short* xcat    = (unsigned short*)alloc((size_t)n*XC*2);  // [3][n][256]
  unsigned short* act     = (unsigned short*)alloc((size_t)n*HC*2);
  unsigned short* w_cat   = (unsigned short*)alloc((size_t)XC*TOT*2);
  unsigned short* w_projb = (unsigned short*)alloc((size_t)HC*HC*2);
  float*          bias_cat= (float*)         alloc((size_t)XC*4);
  int* counts = (int*)alloc((size_t)n*4);
  int* indptr = (int*)alloc((size_t)n*4);
  int* cursor = (int*)alloc((size_t)n*4);
  int4* csrp  = (int4*)alloc((size_t)E*16);
  int  B      = (n + 1023) / 1024;
  int* bsum   = (int*)alloc((size_t)B*4);
  int* boff   = (int*)alloc((size_t)B*4);

  unsigned short* xl_arr = xcat;
  unsigned short* xr_arr = xcat + (size_t)n * HC;
  unsigned short* id_arr = xcat + (size_t)2 * n * HC;

  float* out_final = (float*)d_out;
  float* eattr     = out_final + (size_t)n*HC;

  (void)hipMemsetAsync(counts, 0, (size_t)n*sizeof(int), stream);

  int wtot = 3*TOT*HC + HC*HC + 3*HC;
  k_wprep<<<(wtot + 255)/256, 256, 0, stream>>>(lin_l_w, lin_r_w, res_w, proj_w,
                                                lin_l_b, lin_r_b, res_b,
                                                w_cat, w_projb, bias_cat);

  k_node<<<(n + 3)/4, 256, 0, stream>>>(x, kpts, pts3d, pe_w1, pe_b1, pe_g1, pe_bb1,
                                        pe_w2, pe_b2, pe_g2, pe_bb2, norm_uv, x_comb, n);

  int nbm = (n + 63) / 64;
  k_mfma<TOT, true, true, 2><<<nbm * (XC/128), 256, 0, stream>>>(x_comb, w_cat, bias_cat, xcat, n, XC);

  int eb = (E + 255) / 256;
  k_count<<<eb, 256, 0, stream>>>(ei, counts, E);
  k_scan_part <<<B, 256, 0, stream>>>(counts, bsum, n);
  k_scan_top  <<<1, 64, 0, stream>>>(bsum, boff, B);
  k_scan_write<<<B, 256, 0, stream>>>(counts, boff, indptr, cursor, n);
  k_edge_fill<<<eb, 256, 0, stream>>>(ei, norm_uv, eattr, cursor, csrp, E);

  k_gat2<<<n, 64, 0, stream>>>(indptr, counts, csrp, xl_arr, xr_arr, id_arr,
                               lin_edge_w, att, conv_bias,
                               norm_g, norm_b, post_g, post_b, act, n);

  k_mfma<HC, false, false, 2><<<nbm * (HC/128), 256, 0, stream>>>(act, w_projb, proj_b, out_final, n, HC);
}